// Round 17
// baseline (245.626 us; speedup 1.0000x reference)
//
#include <hip/hip_runtime.h>
#include <math.h>

typedef unsigned short u16;
typedef short short8 __attribute__((ext_vector_type(8)));
typedef short shortv4 __attribute__((ext_vector_type(4)));
typedef float f32x4 __attribute__((ext_vector_type(4)));

#define TXT 224
#define VID 1728
#define S_ALL 1952
#define C_DIM 1920
#define HD 64
#define RANK 128
#define SHD 124928  // 1952*64 per head

// workspace element offsets (u16 units) — total 36,114,432 elts = 72.2 MB
#define OFF_HS   ((size_t)0)          // 2048*1920 bf16
#define OFF_XPAD ((size_t)3932160)    // 2304*1920 bf16 ; aliased: V_tmp (m-major) then attn O
#define OFF_O    OFF_XPAD
#define OFF_HG   ((size_t)8355840)    // 2304*128 bf16
#define OFF_W1T  ((size_t)8650752)    // 128*5760 bf16
#define OFF_W2T  ((size_t)9388032)    // 1920*384 bf16
#define OFF_WQ   ((size_t)10125312)   // 1920*1920 bf16
#define OFF_WK   ((size_t)13811712)
#define OFF_WV   ((size_t)17498112)
#define OFF_WO   ((size_t)21184512)
#define OFF_Q    ((size_t)24870912)   // 30*1952*64 bf16 ; aliased: conv1 f32 partials (5.3MB)
#define OFF_K    ((size_t)28618752)
#define OFF_V    ((size_t)32366592)

__device__ __forceinline__ float b2f(u16 u) {
  union { unsigned int i; float f; } x; x.i = ((unsigned int)u) << 16; return x.f;
}
__device__ __forceinline__ u16 f2b(float f) {
  union { float f; unsigned int i; } x; x.f = f;
  unsigned int i = x.i;
  return (u16)((i + 0x7FFFu + ((i >> 16) & 1u)) >> 16);
}
__device__ __forceinline__ void gload16(const u16* g, short* l) {
  __builtin_amdgcn_global_load_lds((const __attribute__((address_space(1))) unsigned int*)g,
                                   (__attribute__((address_space(3))) unsigned int*)l, 16, 0, 0);
}

// ---- prep (vectorized): f32->bf16 converts + pad zeroing ----------------------------
__global__ void __launch_bounds__(256) prep_kernel(const float* __restrict__ hidden,
                                                   const float* __restrict__ enc,
                                                   const float* __restrict__ w1,
                                                   const float* __restrict__ w2,
                                                   const float* __restrict__ Wq,
                                                   const float* __restrict__ Wk,
                                                   const float* __restrict__ Wv,
                                                   const float* __restrict__ Wo,
                                                   u16* __restrict__ ws) {
  size_t i = (size_t)blockIdx.x * 256 + threadIdx.x;
  if (i < 1105920) {  // Xpad quads: 2304x1920, data rows [216,1944)
    const size_t e = i * 4;
    const int row = (int)(e / 1920), col = (int)(e % 1920);
    shortv4 o4 = {0, 0, 0, 0};
    if (row >= 216 && row < 1944) {
      const float4 f = *(const float4*)(hidden + (size_t)(row - 216) * 1920 + col);
      o4 = (shortv4){(short)f2b(f.x), (short)f2b(f.y), (short)f2b(f.z), (short)f2b(f.w)};
    }
    *(shortv4*)(ws + OFF_XPAD + e) = o4;
    return;
  }
  i -= 1105920;
  if (i < 184320) {  // w1t quads: w1t[r][t*1920+c] = w1[r][c][t]
    const size_t e = i * 4;
    const int r = (int)(e / 5760), j = (int)(e % 5760), t = j / 1920, c = j % 1920;
    const float* s = w1 + (size_t)r * 5760 + (size_t)c * 3 + t;
    shortv4 o4 = {(short)f2b(s[0]), (short)f2b(s[3]), (short)f2b(s[6]), (short)f2b(s[9])};
    *(shortv4*)(ws + OFF_W1T + e) = o4;
    return;
  }
  i -= 184320;
  if (i < 184320) {  // w2t quads: w2t[c][t*128+r] = w2[c][r][t]
    const size_t e = i * 4;
    const int c = (int)(e / 384), j = (int)(e % 384), t = j / 128, r = j % 128;
    const float* s = w2 + (size_t)c * 384 + (size_t)r * 3 + t;
    shortv4 o4 = {(short)f2b(s[0]), (short)f2b(s[3]), (short)f2b(s[6]), (short)f2b(s[9])};
    *(shortv4*)(ws + OFF_W2T + e) = o4;
    return;
  }
  i -= 184320;
  if (i < 107520) {  // hs rows [0,224) from enc
    const size_t e = i * 4;
    const float4 f = *(const float4*)(enc + e);
    *(shortv4*)(ws + OFF_HS + e) =
        (shortv4){(short)f2b(f.x), (short)f2b(f.y), (short)f2b(f.z), (short)f2b(f.w)};
    return;
  }
  i -= 107520;
  if (i < 3686400) {  // WQ,WK,WV,WO quads
    const int j = (int)(i / 921600);
    const size_t e = (i - (size_t)j * 921600) * 4;
    const float* src = (j == 0) ? Wq : ((j == 1) ? Wk : ((j == 2) ? Wv : Wo));
    const float4 f = *(const float4*)(src + e);
    *(shortv4*)(ws + OFF_WQ + (size_t)j * 3686400 + e) =
        (shortv4){(short)f2b(f.x), (short)f2b(f.y), (short)f2b(f.z), (short)f2b(f.w)};
    return;
  }
  i -= 3686400;
  // zero octs (16B): HS pad 23040 | HG low 3456 | HG high 5760 | O pad 23040 = 55296
  const short8 z8 = {0, 0, 0, 0, 0, 0, 0, 0};
  size_t e;
  if (i < 23040) e = OFF_HS + 3747840 + i * 8;
  else if (i < 26496) e = OFF_HG + (i - 23040) * 8;
  else if (i < 32256) e = OFF_HG + 248832 + (i - 26496) * 8;
  else e = OFF_O + 3747840 + (i - 32256) * 8;
  *(short8*)(ws + e) = z8;
}

// ------- BT-layout MFMA GEMM, 2-phase double-buffered: C[M,N] = A[M,K]*B[N,K]^T -----
// grid = nMt * nNt * slices ; slice covers k-steps [slice*ksteps, (slice+1)*ksteps)
// blockIdx remapped via bijective XCD swizzle (m204).
// LOCKED PARAMS (r11/r13/r14 evidence): 128x128 for barrier-bound large-K GEMMs;
// 64-wide BM only where grid-occupancy is BINDING. BK=32, KU=1, direct stores.
// NEW (r17): intra-row XOR swizzle col ^= (row&3)*8 (16B granules, rule #21:
// pre-swizzled global source + swizzled read, linear LDS dest). Demotes the
// 64B-row-stride 8-way ds_read bank conflict to 4-way. Correctness of this
// swizzle pattern was validated end-to-end in the r13 KU=2 run.
struct GArgs {
  const u16 *A, *B0, *B1, *B2;
  const float *bias0, *bias1, *bias2;
  const float *cosp, *sinp, *hidden;
  u16 *out0, *out1, *out2;
  float* outf;
  int lda, ldb, ksteps, spt, tap_rows, nMt, nNt, Mvalid;
};

template <int BM, int BN, int EPI>
__global__ void __launch_bounds__(256) gemm_bt(GArgs a) {
  constexpr int WM = BM / 2, WN = BN / 2, FM = WM / 16, FN = WN / 16;
  __shared__ __align__(16) short lA[2][BM * 32];
  __shared__ __align__(16) short lB[2][BN * 32];
  const int tid = threadIdx.x;
  const int lane = tid & 63;
  const int wv = tid >> 6, wr = wv >> 1, wc = wv & 1;
  const int lr = lane & 15, lg = lane >> 4;
  // bijective XCD swizzle (any grid size): orig%8 -> contiguous chunk
  const int nwg = (int)gridDim.x;
  const int qq = nwg >> 3, rr = nwg & 7;
  const int xx = (int)blockIdx.x & 7, ssb = (int)blockIdx.x >> 3;
  const int bswz = (xx < rr ? xx * (qq + 1) : rr * (qq + 1) + (xx - rr) * qq) + ssb;
  const int mtile = bswz % a.nMt;
  const int ntile_raw = bswz / a.nMt;
  const int ntile = ntile_raw % a.nNt;
  const int slice = ntile_raw / a.nNt;
  const int kstart = slice * a.ksteps;
  const int sec = (ntile * BN) / C_DIM;
  const u16* Bw = (sec == 0) ? a.B0 : ((sec == 1) ? a.B1 : a.B2);
  const int nb = ntile * BN - sec * C_DIM;
  const int m0 = mtile * BM;

  f32x4 acc[FM][FN];
#pragma unroll
  for (int i = 0; i < FM; ++i)
#pragma unroll
    for (int j = 0; j < FN; ++j) acc[i][j] = (f32x4){0.f, 0.f, 0.f, 0.f};

  auto stageStep = [&](int buf, int gs) {
    const int tap = gs / a.spt;
    const int kcol = (gs - tap * a.spt) * 32;
    const int arow0 = m0 + tap * a.tap_rows;
#pragma unroll
    for (int i = 0; i < BM / 64; ++i) {  // A tile [BM][32], 4 chunks/row
      const int c = i * 256 + tid;
      const int row = c >> 2;
      const int colE = ((c & 3) * 8) ^ ((row & 3) * 8);  // pre-swizzled global col
      gload16(a.A + (size_t)(arow0 + row) * a.lda + (kcol + colE), &lA[buf][c * 8]);
    }
#pragma unroll
    for (int i = 0; i < BN / 64; ++i) {  // B tile [BN][32]
      const int c = i * 256 + tid;
      const int row = c >> 2;
      const int colE = ((c & 3) * 8) ^ ((row & 3) * 8);
      gload16(Bw + (size_t)(nb + row) * a.ldb + (gs * 32 + colE), &lB[buf][c * 8]);
    }
  };

  stageStep(0, kstart);
  __syncthreads();  // drain (compiler emits vmcnt(0) before s_barrier)
  int cur = 0;
  for (int s = 0; s < a.ksteps; ++s) {
    if (s + 1 < a.ksteps) stageStep(cur ^ 1, kstart + s + 1);  // overlaps compute below
    short8 af[FM], bfr[FN];
#pragma unroll
    for (int i = 0; i < FM; ++i) {
      const int row = wr * WM + i * 16 + lr;
      af[i] = *(const short8*)(&lA[cur][row * 32 + ((lg * 8) ^ ((row & 3) * 8))]);
    }
#pragma unroll
    for (int j = 0; j < FN; ++j) {
      const int row = wc * WN + j * 16 + lr;
      bfr[j] = *(const short8*)(&lB[cur][row * 32 + ((lg * 8) ^ ((row & 3) * 8))]);
    }
#pragma unroll
    for (int i = 0; i < FM; ++i)
#pragma unroll
      for (int j = 0; j < FN; ++j)
        acc[i][j] = __builtin_amdgcn_mfma_f32_16x16x32_bf16(af[i], bfr[j], acc[i][j], 0, 0, 0);
    __syncthreads();  // one barrier/step: next buf staged + cur reads done
    cur ^= 1;
  }

  // epilogue: C/D layout col=lane&15, row=(lane>>4)*4+reg  [m89-verified]
#pragma unroll
  for (int i = 0; i < FM; ++i) {
#pragma unroll
    for (int j = 0; j < FN; ++j) {
      const int col = ntile * BN + wc * WN + j * 16 + lr;
#pragma unroll
      for (int r = 0; r < 4; ++r) {
        const int m = m0 + wr * WM + i * 16 + lg * 4 + r;
        float v = acc[i][j][r];
        if (EPI == 4) {  // conv1 split-K: raw f32 partial
          if (m < a.Mvalid) a.outf[(size_t)slice * 221184 + (size_t)m * RANK + col] = v;
        } else if (EPI == 1) {  // conv2: + hidden -> hs video rows (bf16)
          if (m < a.Mvalid) {
            v += a.hidden[(size_t)m * C_DIM + col];
            a.out0[(size_t)m * C_DIM + col] = f2b(v);
          }
        } else if (EPI == 2) {  // qkv: bias + RoPE + scale, head-major m-major stores
          const int nn = col - sec * C_DIM;
          const int hh = nn >> 6, d = nn & 63;
          const float* bias = (sec == 0) ? a.bias0 : ((sec == 1) ? a.bias1 : a.bias2);
          v += bias[nn];
          const float vp = __shfl_xor(v, 1);  // partner column (d^1) value
          if (sec < 2 && m >= TXT) {
            const int vid = ((m < S_ALL) ? m : TXT) - TXT;  // clamp masked rows
            const float c = a.cosp[vid * HD + d];
            const float sn = a.sinp[vid * HD + d];
            v = (d & 1) ? (v * c + vp * sn) : (v * c - vp * sn);
          }
          if (sec == 0) v *= 0.18033688011112042f;  // HD^-0.5 * log2(e) folded into q
          if (m < a.Mvalid) {
            u16* dst = (sec == 0) ? a.out0 : ((sec == 1) ? a.out1 : a.out2);
            dst[(size_t)hh * SHD + (size_t)m * HD + d] = f2b(v);
          }
        } else {  // EPI 3: out-proj, bias + output row remap, f32 direct stores
          v += a.bias0[col];
          if (m < a.Mvalid) {
            const int dr = (m >= TXT) ? (m - TXT) : (VID + m);
            a.outf[(size_t)dr * C_DIM + col] = v;
          }
        }
      }
    }
  }
}

// ---- conv1 reduce: sum 6 split-K partials + exact GELU -> Hg interior ---------------
__global__ void __launch_bounds__(256) c1reduce_kernel(const float* __restrict__ part,
                                                       u16* __restrict__ hg) {
  const int i = blockIdx.x * 256 + threadIdx.x;  // 221184 = 1728*128
  float s = 0.f;
#pragma unroll
  for (int j = 0; j < 6; ++j) s += part[(size_t)j * 221184 + i];
  const float g = 0.5f * s * (1.0f + erff(s * 0.70710678f));
  hg[i] = f2b(g);
}

// ---- V transpose: [m][d] m-major -> [d][m] d-major per head -------------------------
__global__ void __launch_bounds__(256) vtrans_kernel(const u16* __restrict__ vin,
                                                     u16* __restrict__ vout) {
  __shared__ u16 t[64][72];
  const int b = blockIdx.x, hh = b / 31, mt = b % 31;
  const int m0 = mt * 64;
  const int rows = (m0 + 64 <= S_ALL) ? 64 : (S_ALL - m0);  // 64 or 32 (last tile)
  const int tid = threadIdx.x;
  const u16* src = vin + (size_t)hh * SHD + (size_t)m0 * HD;
#pragma unroll
  for (int p = 0; p < 2; ++p) {
    const int r = p * 32 + (tid >> 3), c = (tid & 7) * 8;
    short8 v8 = {0, 0, 0, 0, 0, 0, 0, 0};
    if (r < rows) v8 = *(const short8*)(src + (size_t)r * HD + c);
    *(short8*)&t[r][c] = v8;
  }
  __syncthreads();
  const int d = tid & 63, ms = tid >> 6;  // ms 0..3, 16 m-values each
  if (ms * 16 < rows) {
    short8 a0, a1;
#pragma unroll
    for (int x = 0; x < 8; ++x) { a0[x] = (short)t[ms * 16 + x][d]; a1[x] = (short)t[ms * 16 + 8 + x][d]; }
    u16* dst = vout + (size_t)hh * SHD + (size_t)d * S_ALL + m0 + ms * 16;
    *(short8*)dst = a0;
    *(short8*)(dst + 8) = a1;
  }
}

// ---- flash attention v8: K+V LDS dbuf, swapped QK^T, KVBLK=64, per-wave P LDS, ------
// cvt_pk, XCD swizzle, max-free softmax (scores provably small), deferred l-reduction.
__global__ void __launch_bounds__(256) attn_kernel(const u16* __restrict__ q,
                                                   const u16* __restrict__ k,
                                                   const u16* __restrict__ vT,
                                                   u16* __restrict__ o) {
  __shared__ __align__(16) short lK[2][4096];  // [64 k][64 d], col ^= (row&7)*8
  __shared__ __align__(16) short lV[2][4096];  // [64 d][64 k], col ^= (row&7)*8
  __shared__ __align__(16) short lp[4][1024];  // per-wave P [16 q][64 k], col ^= (q&7)*8
  // bijective XCD swizzle: 930 = 8*116 + 2 ; blocks sharing a head -> same XCD L2
  const int xcd = blockIdx.x & 7, idx = blockIdx.x >> 3;
  const int bid = (xcd < 2) ? (xcd * 117 + idx) : (234 + (xcd - 2) * 116 + idx);
  const int hh = bid / 31, qt = bid - hh * 31;
  const int tid = threadIdx.x, wv = tid >> 6, lane = tid & 63;
  const int lr = lane & 15, lg = lane >> 4;
  const int qbase = qt * 64 + wv * 16;
  const bool active = qbase < S_ALL;  // inactive waves still stage + barrier
  const u16* qh = q + (size_t)hh * SHD;
  const u16* kh = k + (size_t)hh * SHD;
  const u16* vh = vT + (size_t)hh * SHD;

  // staging geometry: thread covers 2 x 16B chunks of K tile and of V tile
  int krow[2], kcol[2], kdst[2];
#pragma unroll
  for (int j = 0; j < 2; ++j) {
    const int p0 = (j * 256 + tid) * 8;  // u16 dest offset, linear
    const int row = p0 >> 6, cs = p0 & 63;
    kdst[j] = p0;
    krow[j] = row;
    kcol[j] = cs ^ ((row & 7) * 8);  // pre-swizzled global col
  }

  short8 aq0 = {}, aq1 = {};
  if (active) {
    aq0 = *(const short8*)(qh + (size_t)(qbase + lr) * HD + lg * 8);
    aq1 = *(const short8*)(qh + (size_t)(qbase + lr) * HD + 32 + lg * 8);
  }
  f32x4 oa[4];
#pragma unroll
  for (int gd = 0; gd < 4; ++gd) oa[gd] = (f32x4){0.f, 0.f, 0.f, 0.f};
  float lw = 0.f;  // per-lane PARTIAL row-sum; reduced across lane groups at the end
  const f32x4 z4 = (f32x4){0.f, 0.f, 0.f, 0.f};
  const int pmask = (lr & 7) * 8;
  short* lpw = &lp[wv][0];

  // prologue: stage tile 0 into buf 0
#pragma unroll
  for (int j = 0; j < 2; ++j) gload16(kh + (size_t)krow[j] * HD + kcol[j], &lK[0][kdst[j]]);
#pragma unroll
  for (int j = 0; j < 2; ++j) gload16(vh + (size_t)krow[j] * S_ALL + kcol[j], &lV[0][kdst[j]]);
  __syncthreads();

  int cur = 0;
  for (int t = 0; t < 30; ++t) {
    const int kb = t * 64;
    if (t < 29) {  // stage tile t+1 into buf cur^1 (overlaps compute below)
#pragma unroll
      for (int j = 0; j < 2; ++j)
        gload16(kh + (size_t)(kb + 64 + krow[j]) * HD + kcol[j], &lK[cur ^ 1][kdst[j]]);
#pragma unroll
      for (int j = 0; j < 2; ++j)
        gload16(vh + (size_t)krow[j] * S_ALL + (kb + 64 + kcol[j]), &lV[cur ^ 1][kdst[j]]);
    }
    if (active) {
      const short* Kt = &lK[cur][0];
      const short* Vt = &lV[cur][0];
      f32x4 st[4];
      __builtin_amdgcn_s_setprio(1);
#pragma unroll
      for (int k16 = 0; k16 < 4; ++k16) {
        const int row = k16 * 16 + lr;
        const int m8 = (row & 7) * 8;
        short8 kf0 = *(const short8*)(Kt + row * 64 + ((lg * 8) ^ m8));
        short8 kf1 = *(const short8*)(Kt + row * 64 + ((32 + lg * 8) ^ m8));
        st[k16] = __builtin_amdgcn_mfma_f32_16x16x32_bf16(kf0, aq0, z4, 0, 0, 0);
        st[k16] = __builtin_amdgcn_mfma_f32_16x16x32_bf16(kf1, aq1, st[k16], 0, 0, 0);
      }
      __builtin_amdgcn_s_setprio(0);
      // max-free softmax: P = exp2(s) directly; per-lane partial l (no in-loop shfl)
      float rs = 0.f;
#pragma unroll
      for (int k16 = 0; k16 < 4; ++k16) {
        float p0 = __builtin_exp2f(st[k16][0]);
        float p1 = __builtin_exp2f(st[k16][1]);
        float p2 = __builtin_exp2f(st[k16][2]);
        float p3 = __builtin_exp2f(st[k16][3]);
        rs += (p0 + p1) + (p2 + p3);
        uint2 pk;
        asm("v_cvt_pk_bf16_f32 %0, %1, %2" : "=v"(pk.x) : "v"(p0), "v"(p1));
        asm("v_cvt_pk_bf16_f32 %0, %1, %2" : "=v"(pk.y) : "v"(p2), "v"(p3));
        *(uint2*)(lpw + lr * 64 + ((k16 * 16 + lg * 4) ^ pmask)) = pk;
      }
      lw += rs;
      asm volatile("s_waitcnt lgkmcnt(0)" ::: "memory");  // wave-synchronous LDS handoff
      short8 pa0 = *(const short8*)(lpw + lr * 64 + ((lg * 8) ^ pmask));
      short8 pa1 = *(const short8*)(lpw + lr * 64 + ((32 + lg * 8) ^ pmask));
      __builtin_amdgcn_s_setprio(1);
#pragma unroll
      for (int gd = 0; gd < 4; ++gd) {
        const int row = gd * 16 + lr;
        const int m8 = (row & 7) * 8;
        short8 vf0 = *(const short8*)(Vt + row * 64 + ((lg * 8) ^ m8));
        short8 vf1 = *(const short8*)(Vt + row * 64 + ((32 + lg * 8) ^ m8));
        f32x4 tacc = __builtin_amdgcn_mfma_f32_16x16x32_bf16(pa0, vf0, oa[gd], 0, 0, 0);
        oa[gd] = __builtin_amdgcn_mfma_f32_16x16x32_bf16(pa1, vf1, tacc, 0, 0, 0);
      }
      __builtin_amdgcn_s_setprio(0);
    }
    __syncthreads();
    cur ^= 1;
  }

  if (active) {  // tail: 32 keys [1920,1952), K/V direct from global (in-bounds exactly)
    const u16* kp = kh + (size_t)1920 * HD;
    short8 kf00 = *(const short8*)(kp + (size_t)lr * HD + lg * 8);
    short8 kf01 = *(const short8*)(kp + (size_t)lr * HD + 32 + lg * 8);
    short8 kf10 = *(const short8*)(kp + (size_t)(16 + lr) * HD + lg * 8);
    short8 kf11 = *(const short8*)(kp + (size_t)(16 + lr) * HD + 32 + lg * 8);
    f32x4 st0 = __builtin_amdgcn_mfma_f32_16x16x32_bf16(kf00, aq0, z4, 0, 0, 0);
    st0 = __builtin_amdgcn_mfma_f32_16x16x32_bf16(kf01, aq1, st0, 0, 0, 0);
    f32x4 st1 = __builtin_amdgcn_mfma_f32_16x16x32_bf16(kf10, aq0, z4, 0, 0, 0);
    st1 = __builtin_amdgcn_mfma_f32_16x16x32_bf16(kf11, aq1, st1, 0, 0, 0);
    float rs = 0.f;
    float pp[8];
#pragma unroll
    for (int r = 0; r < 4; ++r) { pp[r] = __builtin_exp2f(st0[r]); rs += pp[r]; }
#pragma unroll
    for (int r = 0; r < 4; ++r) { pp[4 + r] = __builtin_exp2f(st1[r]); rs += pp[4 + r]; }
    {
      uint2 pk;
      asm("v_cvt_pk_bf16_f32 %0, %1, %2" : "=v"(pk.x) : "v"(pp[0]), "v"(pp[1]));
      asm("v_cvt_pk_bf16_f32 %0, %1, %2" : "=v"(pk.y) : "v"(pp[2]), "v"(pp[3]));
      *(uint2*)(lpw + lr * 64 + ((lg * 4) ^ pmask)) = pk;
      asm("v_cvt_pk_bf16_f32 %0, %1, %2" : "=v"(pk.x) : "v"(pp[4]), "v"(pp[5]));
      asm("v_cvt_pk_bf16_f32 %0, %1, %2" : "=v"(pk.y) : "v"(pp[6]), "v"(pp[7]));
      *(uint2*)(lpw + lr * 64 + ((16 + lg * 4) ^ pmask)) = pk;
    }
    lw += rs;
    asm volatile("s_waitcnt lgkmcnt(0)" ::: "memory");
    short8 pa0 = *(const short8*)(lpw + lr * 64 + ((lg * 8) ^ pmask));
#pragma unroll
    for (int gd = 0; gd < 4; ++gd) {
      short8 vf = *(const short8*)(vh + (size_t)(gd * 16 + lr) * S_ALL + 1920 + lg * 8);
      oa[gd] = __builtin_amdgcn_mfma_f32_16x16x32_bf16(pa0, vf, oa[gd], 0, 0, 0);
    }
    // deferred l-reduction: sum the 4 lane-group partials once, then distribute
    lw += __shfl_xor(lw, 16);
    lw += __shfl_xor(lw, 32);
    // final: O[q][hh*64+d], q at reg dim (lg*4+r), d at lr dim
    float lwp[4];
#pragma unroll
    for (int r = 0; r < 4; ++r) lwp[r] = 1.0f / __shfl(lw, lg * 4 + r);
#pragma unroll
    for (int gd = 0; gd < 4; ++gd) {
      const int col = hh * HD + gd * 16 + lr;
#pragma unroll
      for (int r = 0; r < 4; ++r) {
        const int m = qbase + lg * 4 + r;
        o[(size_t)m * C_DIM + col] = f2b(oa[gd][r] * lwp[r]);
      }
    }
  }
}

// ---------------- launch ------------------------------------------------------------
extern "C" void kernel_launch(void* const* d_in, const int* in_sizes, int n_in,
                              void* d_out, int out_size, void* d_ws, size_t ws_size,
                              hipStream_t stream) {
  const float* hidden = (const float*)d_in[0];
  const float* enc = (const float*)d_in[1];
  const float* cosp = (const float*)d_in[2];
  const float* sinp = (const float*)d_in[3];
  const float* w1 = (const float*)d_in[4];
  const float* w2 = (const float*)d_in[5];
  const float* bq = (const float*)d_in[7];
  const float* bk = (const float*)d_in[9];
  const float* bv = (const float*)d_in[11];
  const float* bo = (const float*)d_in[13];
  u16* ws = (u16*)d_ws;
  float* out = (float*)d_out;

  prep_kernel<<<20796, 256, 0, stream>>>(hidden, enc, w1, w2, (const float*)d_in[6],
                                         (const float*)d_in[8], (const float*)d_in[10],
                                         (const float*)d_in[12], ws);

  GArgs c1{};  // conv1 split-K: M=1728 N=128, 6 slices x 30 steps, f32 partials
  c1.A = ws + OFF_XPAD; c1.B0 = c1.B1 = c1.B2 = ws + OFF_W1T;
  c1.lda = C_DIM; c1.ldb = 5760; c1.ksteps = 30; c1.spt = 60; c1.tap_rows = 216;
  c1.nMt = 27; c1.nNt = 2; c1.Mvalid = VID;
  c1.outf = (float*)(ws + OFF_Q);
  gemm_bt<64, 64, 4><<<324, 256, 0, stream>>>(c1);

  c1reduce_kernel<<<864, 256, 0, stream>>>((const float*)(ws + OFF_Q),
                                           ws + OFF_HG + (size_t)216 * RANK);

  GArgs c2{};  // conv2: M=1728 N=1920 K=3x128, 64x128 tiles -> 405 blocks
  c2.A = ws + OFF_HG; c2.B0 = c2.B1 = c2.B2 = ws + OFF_W2T;
  c2.lda = RANK; c2.ldb = 384; c2.ksteps = 12; c2.spt = 4; c2.tap_rows = 216;
  c2.nMt = 27; c2.nNt = 15; c2.Mvalid = VID; c2.hidden = hidden;
  c2.out0 = ws + OFF_HS + (size_t)TXT * C_DIM;
  gemm_bt<64, 128, 1><<<405, 256, 0, stream>>>(c2);

  GArgs c3{};  // fused QKV: M=1952 N=3x1920 K=1920, 128x128 KU=1 (proven best)
  c3.A = ws + OFF_HS; c3.B0 = ws + OFF_WQ; c3.B1 = ws + OFF_WK; c3.B2 = ws + OFF_WV;
  c3.bias0 = bq; c3.bias1 = bk; c3.bias2 = bv; c3.cosp = cosp; c3.sinp = sinp;
  c3.lda = C_DIM; c3.ldb = C_DIM; c3.ksteps = 60; c3.spt = 60; c3.tap_rows = 0;
  c3.nMt = 16; c3.nNt = 45; c3.Mvalid = S_ALL;
  c3.out0 = ws + OFF_Q; c3.out1 = ws + OFF_K; c3.out2 = ws + OFF_O;
  gemm_bt<128, 128, 2><<<720, 256, 0, stream>>>(c3);

  vtrans_kernel<<<930, 256, 0, stream>>>(ws + OFF_O, ws + OFF_V);  // V -> d-major

  attn_kernel<<<930, 256, 0, stream>>>(ws + OFF_Q, ws + OFF_K, ws + OFF_V, ws + OFF_O);

  GArgs c4{};  // out-proj: M=1952 N=1920 K=1920, 64x128 direct-store (r10 proven)
  c4.A = ws + OFF_O; c4.B0 = c4.B1 = c4.B2 = ws + OFF_WO; c4.bias0 = bo;
  c4.lda = C_DIM; c4.ldb = C_DIM; c4.ksteps = 60; c4.spt = 60; c4.tap_rows = 0;
  c4.nMt = 32; c4.nNt = 15; c4.Mvalid = S_ALL;
  c4.outf = out;
  gemm_bt<64, 128, 3><<<480, 256, 0, stream>>>(c4);
}

// Round 18
// 243.760 us; speedup vs baseline: 1.0077x; 1.0077x over previous
//
#include <hip/hip_runtime.h>
#include <math.h>

typedef unsigned short u16;
typedef short short8 __attribute__((ext_vector_type(8)));
typedef short shortv4 __attribute__((ext_vector_type(4)));
typedef float f32x4 __attribute__((ext_vector_type(4)));

#define TXT 224
#define VID 1728
#define S_ALL 1952
#define C_DIM 1920
#define HD 64
#define RANK 128
#define SHD 124928  // 1952*64 per head

// workspace element offsets (u16 units) — total 36,114,432 elts = 72.2 MB
#define OFF_HS   ((size_t)0)          // 2048*1920 bf16
#define OFF_XPAD ((size_t)3932160)    // 2304*1920 bf16 ; aliased: V_tmp (m-major) then attn O
#define OFF_O    OFF_XPAD
#define OFF_HG   ((size_t)8355840)    // 2304*128 bf16
#define OFF_W1T  ((size_t)8650752)    // 128*5760 bf16
#define OFF_W2T  ((size_t)9388032)    // 1920*384 bf16
#define OFF_WQ   ((size_t)10125312)   // 1920*1920 bf16
#define OFF_WK   ((size_t)13811712)
#define OFF_WV   ((size_t)17498112)
#define OFF_WO   ((size_t)21184512)
#define OFF_Q    ((size_t)24870912)   // 30*1952*64 bf16 ; aliased: conv1 f32 partials (5.3MB)
#define OFF_K    ((size_t)28618752)
#define OFF_V    ((size_t)32366592)

__device__ __forceinline__ float b2f(u16 u) {
  union { unsigned int i; float f; } x; x.i = ((unsigned int)u) << 16; return x.f;
}
__device__ __forceinline__ u16 f2b(float f) {
  union { float f; unsigned int i; } x; x.f = f;
  unsigned int i = x.i;
  return (u16)((i + 0x7FFFu + ((i >> 16) & 1u)) >> 16);
}
__device__ __forceinline__ void gload16(const u16* g, short* l) {
  __builtin_amdgcn_global_load_lds((const __attribute__((address_space(1))) unsigned int*)g,
                                   (__attribute__((address_space(3))) unsigned int*)l, 16, 0, 0);
}

// ---- prep (vectorized): f32->bf16 converts + pad zeroing ----------------------------
__global__ void __launch_bounds__(256) prep_kernel(const float* __restrict__ hidden,
                                                   const float* __restrict__ enc,
                                                   const float* __restrict__ w1,
                                                   const float* __restrict__ w2,
                                                   const float* __restrict__ Wq,
                                                   const float* __restrict__ Wk,
                                                   const float* __restrict__ Wv,
                                                   const float* __restrict__ Wo,
                                                   u16* __restrict__ ws) {
  size_t i = (size_t)blockIdx.x * 256 + threadIdx.x;
  if (i < 1105920) {  // Xpad quads: 2304x1920, data rows [216,1944)
    const size_t e = i * 4;
    const int row = (int)(e / 1920), col = (int)(e % 1920);
    shortv4 o4 = {0, 0, 0, 0};
    if (row >= 216 && row < 1944) {
      const float4 f = *(const float4*)(hidden + (size_t)(row - 216) * 1920 + col);
      o4 = (shortv4){(short)f2b(f.x), (short)f2b(f.y), (short)f2b(f.z), (short)f2b(f.w)};
    }
    *(shortv4*)(ws + OFF_XPAD + e) = o4;
    return;
  }
  i -= 1105920;
  if (i < 184320) {  // w1t quads: w1t[r][t*1920+c] = w1[r][c][t]
    const size_t e = i * 4;
    const int r = (int)(e / 5760), j = (int)(e % 5760), t = j / 1920, c = j % 1920;
    const float* s = w1 + (size_t)r * 5760 + (size_t)c * 3 + t;
    shortv4 o4 = {(short)f2b(s[0]), (short)f2b(s[3]), (short)f2b(s[6]), (short)f2b(s[9])};
    *(shortv4*)(ws + OFF_W1T + e) = o4;
    return;
  }
  i -= 184320;
  if (i < 184320) {  // w2t quads: w2t[c][t*128+r] = w2[c][r][t]
    const size_t e = i * 4;
    const int c = (int)(e / 384), j = (int)(e % 384), t = j / 128, r = j % 128;
    const float* s = w2 + (size_t)c * 384 + (size_t)r * 3 + t;
    shortv4 o4 = {(short)f2b(s[0]), (short)f2b(s[3]), (short)f2b(s[6]), (short)f2b(s[9])};
    *(shortv4*)(ws + OFF_W2T + e) = o4;
    return;
  }
  i -= 184320;
  if (i < 107520) {  // hs rows [0,224) from enc
    const size_t e = i * 4;
    const float4 f = *(const float4*)(enc + e);
    *(shortv4*)(ws + OFF_HS + e) =
        (shortv4){(short)f2b(f.x), (short)f2b(f.y), (short)f2b(f.z), (short)f2b(f.w)};
    return;
  }
  i -= 107520;
  if (i < 3686400) {  // WQ,WK,WV,WO quads
    const int j = (int)(i / 921600);
    const size_t e = (i - (size_t)j * 921600) * 4;
    const float* src = (j == 0) ? Wq : ((j == 1) ? Wk : ((j == 2) ? Wv : Wo));
    const float4 f = *(const float4*)(src + e);
    *(shortv4*)(ws + OFF_WQ + (size_t)j * 3686400 + e) =
        (shortv4){(short)f2b(f.x), (short)f2b(f.y), (short)f2b(f.z), (short)f2b(f.w)};
    return;
  }
  i -= 3686400;
  // zero octs (16B): HS pad 23040 | HG low 3456 | HG high 5760 | O pad 23040 = 55296
  const short8 z8 = {0, 0, 0, 0, 0, 0, 0, 0};
  size_t e;
  if (i < 23040) e = OFF_HS + 3747840 + i * 8;
  else if (i < 26496) e = OFF_HG + (i - 23040) * 8;
  else if (i < 32256) e = OFF_HG + 248832 + (i - 26496) * 8;
  else e = OFF_O + 3747840 + (i - 32256) * 8;
  *(short8*)(ws + e) = z8;
}

// ------- BT-layout MFMA GEMM, 2-phase double-buffered: C[M,N] = A[M,K]*B[N,K]^T -----
// grid = nMt * nNt * slices ; slice covers k-steps [slice*ksteps, (slice+1)*ksteps)
// blockIdx remapped via bijective XCD swizzle (m204).
// LOCKED PARAMS (r11/r13/r14/r17 evidence): 128x128 for barrier-bound large-K GEMMs;
// 64-wide BM only where grid-occupancy is BINDING (<1 block/CU). BK=32, KU=1,
// direct stores (no atomics), linear LDS (read-swizzle measured neutral, r17).
struct GArgs {
  const u16 *A, *B0, *B1, *B2;
  const float *bias0, *bias1, *bias2;
  const float *cosp, *sinp, *hidden;
  u16 *out0, *out1, *out2;
  float* outf;
  int lda, ldb, ksteps, spt, tap_rows, nMt, nNt, Mvalid;
};

template <int BM, int BN, int EPI>
__global__ void __launch_bounds__(256) gemm_bt(GArgs a) {
  constexpr int WM = BM / 2, WN = BN / 2, FM = WM / 16, FN = WN / 16;
  __shared__ __align__(16) short lA[2][BM * 32];
  __shared__ __align__(16) short lB[2][BN * 32];
  const int tid = threadIdx.x;
  const int lane = tid & 63;
  const int wv = tid >> 6, wr = wv >> 1, wc = wv & 1;
  const int lr = lane & 15, lg = lane >> 4;
  // bijective XCD swizzle (any grid size): orig%8 -> contiguous chunk
  const int nwg = (int)gridDim.x;
  const int qq = nwg >> 3, rr = nwg & 7;
  const int xx = (int)blockIdx.x & 7, ssb = (int)blockIdx.x >> 3;
  const int bswz = (xx < rr ? xx * (qq + 1) : rr * (qq + 1) + (xx - rr) * qq) + ssb;
  const int mtile = bswz % a.nMt;
  const int ntile_raw = bswz / a.nMt;
  const int ntile = ntile_raw % a.nNt;
  const int slice = ntile_raw / a.nNt;
  const int kstart = slice * a.ksteps;
  const int sec = (ntile * BN) / C_DIM;
  const u16* Bw = (sec == 0) ? a.B0 : ((sec == 1) ? a.B1 : a.B2);
  const int nb = ntile * BN - sec * C_DIM;
  const int m0 = mtile * BM;

  f32x4 acc[FM][FN];
#pragma unroll
  for (int i = 0; i < FM; ++i)
#pragma unroll
    for (int j = 0; j < FN; ++j) acc[i][j] = (f32x4){0.f, 0.f, 0.f, 0.f};

  auto stageStep = [&](int buf, int gs) {
    const int tap = gs / a.spt;
    const int kcol = (gs - tap * a.spt) * 32;
    const int arow0 = m0 + tap * a.tap_rows;
#pragma unroll
    for (int i = 0; i < BM / 64; ++i) {  // A tile [BM][32]
      const int o = (i * 256 + tid) * 16;
      const int row = o >> 6;
      const int ke = (o & 63) >> 1;
      gload16(a.A + (size_t)(arow0 + row) * a.lda + (kcol + ke), &lA[buf][o >> 1]);
    }
#pragma unroll
    for (int i = 0; i < BN / 64; ++i) {  // B tile [BN][32]
      const int o = (i * 256 + tid) * 16;
      const int row = o >> 6;
      const int ke = (o & 63) >> 1;
      gload16(Bw + (size_t)(nb + row) * a.ldb + (gs * 32 + ke), &lB[buf][o >> 1]);
    }
  };

  stageStep(0, kstart);
  __syncthreads();  // drain (compiler emits vmcnt(0) before s_barrier)
  int cur = 0;
  for (int s = 0; s < a.ksteps; ++s) {
    if (s + 1 < a.ksteps) stageStep(cur ^ 1, kstart + s + 1);  // overlaps compute below
    short8 af[FM], bfr[FN];
#pragma unroll
    for (int i = 0; i < FM; ++i)
      af[i] = *(const short8*)(&lA[cur][(wr * WM + i * 16 + lr) * 32 + lg * 8]);
#pragma unroll
    for (int j = 0; j < FN; ++j)
      bfr[j] = *(const short8*)(&lB[cur][(wc * WN + j * 16 + lr) * 32 + lg * 8]);
#pragma unroll
    for (int i = 0; i < FM; ++i)
#pragma unroll
      for (int j = 0; j < FN; ++j)
        acc[i][j] = __builtin_amdgcn_mfma_f32_16x16x32_bf16(af[i], bfr[j], acc[i][j], 0, 0, 0);
    __syncthreads();  // one barrier/step: next buf staged + cur reads done
    cur ^= 1;
  }

  // epilogue: C/D layout col=lane&15, row=(lane>>4)*4+reg  [m89-verified]
#pragma unroll
  for (int i = 0; i < FM; ++i) {
#pragma unroll
    for (int j = 0; j < FN; ++j) {
      const int col = ntile * BN + wc * WN + j * 16 + lr;
#pragma unroll
      for (int r = 0; r < 4; ++r) {
        const int m = m0 + wr * WM + i * 16 + lg * 4 + r;
        float v = acc[i][j][r];
        if (EPI == 4) {  // conv1 split-K: raw f32 partial
          if (m < a.Mvalid) a.outf[(size_t)slice * 221184 + (size_t)m * RANK + col] = v;
        } else if (EPI == 1) {  // conv2: + hidden -> hs video rows (bf16)
          if (m < a.Mvalid) {
            v += a.hidden[(size_t)m * C_DIM + col];
            a.out0[(size_t)m * C_DIM + col] = f2b(v);
          }
        } else if (EPI == 2) {  // qkv: bias + RoPE + scale, head-major m-major stores
          const int nn = col - sec * C_DIM;
          const int hh = nn >> 6, d = nn & 63;
          const float* bias = (sec == 0) ? a.bias0 : ((sec == 1) ? a.bias1 : a.bias2);
          v += bias[nn];
          const float vp = __shfl_xor(v, 1);  // partner column (d^1) value
          if (sec < 2 && m >= TXT) {
            const int vid = ((m < S_ALL) ? m : TXT) - TXT;  // clamp masked rows
            const float c = a.cosp[vid * HD + d];
            const float sn = a.sinp[vid * HD + d];
            v = (d & 1) ? (v * c + vp * sn) : (v * c - vp * sn);
          }
          if (sec == 0) v *= 0.18033688011112042f;  // HD^-0.5 * log2(e) folded into q
          if (m < a.Mvalid) {
            u16* dst = (sec == 0) ? a.out0 : ((sec == 1) ? a.out1 : a.out2);
            dst[(size_t)hh * SHD + (size_t)m * HD + d] = f2b(v);
          }
        } else {  // EPI 3: out-proj, bias + output row remap, f32 direct stores
          v += a.bias0[col];
          if (m < a.Mvalid) {
            const int dr = (m >= TXT) ? (m - TXT) : (VID + m);
            a.outf[(size_t)dr * C_DIM + col] = v;
          }
        }
      }
    }
  }
}

// ---- conv1 reduce: sum 6 split-K partials + exact GELU -> Hg interior ---------------
__global__ void __launch_bounds__(256) c1reduce_kernel(const float* __restrict__ part,
                                                       u16* __restrict__ hg) {
  const int i = blockIdx.x * 256 + threadIdx.x;  // 221184 = 1728*128
  float s = 0.f;
#pragma unroll
  for (int j = 0; j < 6; ++j) s += part[(size_t)j * 221184 + i];
  const float g = 0.5f * s * (1.0f + erff(s * 0.70710678f));
  hg[i] = f2b(g);
}

// ---- V transpose: [m][d] m-major -> [d][m] d-major per head -------------------------
__global__ void __launch_bounds__(256) vtrans_kernel(const u16* __restrict__ vin,
                                                     u16* __restrict__ vout) {
  __shared__ u16 t[64][72];
  const int b = blockIdx.x, hh = b / 31, mt = b % 31;
  const int m0 = mt * 64;
  const int rows = (m0 + 64 <= S_ALL) ? 64 : (S_ALL - m0);  // 64 or 32 (last tile)
  const int tid = threadIdx.x;
  const u16* src = vin + (size_t)hh * SHD + (size_t)m0 * HD;
#pragma unroll
  for (int p = 0; p < 2; ++p) {
    const int r = p * 32 + (tid >> 3), c = (tid & 7) * 8;
    short8 v8 = {0, 0, 0, 0, 0, 0, 0, 0};
    if (r < rows) v8 = *(const short8*)(src + (size_t)r * HD + c);
    *(short8*)&t[r][c] = v8;
  }
  __syncthreads();
  const int d = tid & 63, ms = tid >> 6;  // ms 0..3, 16 m-values each
  if (ms * 16 < rows) {
    short8 a0, a1;
#pragma unroll
    for (int x = 0; x < 8; ++x) { a0[x] = (short)t[ms * 16 + x][d]; a1[x] = (short)t[ms * 16 + 8 + x][d]; }
    u16* dst = vout + (size_t)hh * SHD + (size_t)d * S_ALL + m0 + ms * 16;
    *(short8*)dst = a0;
    *(short8*)(dst + 8) = a1;
  }
}

// ---- flash attention v8: K+V LDS dbuf, swapped QK^T, KVBLK=64, per-wave P LDS, ------
// cvt_pk, XCD swizzle, max-free softmax (scores provably small), deferred l-reduction.
__global__ void __launch_bounds__(256) attn_kernel(const u16* __restrict__ q,
                                                   const u16* __restrict__ k,
                                                   const u16* __restrict__ vT,
                                                   u16* __restrict__ o) {
  __shared__ __align__(16) short lK[2][4096];  // [64 k][64 d], col ^= (row&7)*8
  __shared__ __align__(16) short lV[2][4096];  // [64 d][64 k], col ^= (row&7)*8
  __shared__ __align__(16) short lp[4][1024];  // per-wave P [16 q][64 k], col ^= (q&7)*8
  // bijective XCD swizzle: 930 = 8*116 + 2 ; blocks sharing a head -> same XCD L2
  const int xcd = blockIdx.x & 7, idx = blockIdx.x >> 3;
  const int bid = (xcd < 2) ? (xcd * 117 + idx) : (234 + (xcd - 2) * 116 + idx);
  const int hh = bid / 31, qt = bid - hh * 31;
  const int tid = threadIdx.x, wv = tid >> 6, lane = tid & 63;
  const int lr = lane & 15, lg = lane >> 4;
  const int qbase = qt * 64 + wv * 16;
  const bool active = qbase < S_ALL;  // inactive waves still stage + barrier
  const u16* qh = q + (size_t)hh * SHD;
  const u16* kh = k + (size_t)hh * SHD;
  const u16* vh = vT + (size_t)hh * SHD;

  // staging geometry: thread covers 2 x 16B chunks of K tile and of V tile
  int krow[2], kcol[2], kdst[2];
#pragma unroll
  for (int j = 0; j < 2; ++j) {
    const int p0 = (j * 256 + tid) * 8;  // u16 dest offset, linear
    const int row = p0 >> 6, cs = p0 & 63;
    kdst[j] = p0;
    krow[j] = row;
    kcol[j] = cs ^ ((row & 7) * 8);  // pre-swizzled global col
  }

  short8 aq0 = {}, aq1 = {};
  if (active) {
    aq0 = *(const short8*)(qh + (size_t)(qbase + lr) * HD + lg * 8);
    aq1 = *(const short8*)(qh + (size_t)(qbase + lr) * HD + 32 + lg * 8);
  }
  f32x4 oa[4];
#pragma unroll
  for (int gd = 0; gd < 4; ++gd) oa[gd] = (f32x4){0.f, 0.f, 0.f, 0.f};
  float lw = 0.f;  // per-lane PARTIAL row-sum; reduced across lane groups at the end
  const f32x4 z4 = (f32x4){0.f, 0.f, 0.f, 0.f};
  const int pmask = (lr & 7) * 8;
  short* lpw = &lp[wv][0];

  // prologue: stage tile 0 into buf 0
#pragma unroll
  for (int j = 0; j < 2; ++j) gload16(kh + (size_t)krow[j] * HD + kcol[j], &lK[0][kdst[j]]);
#pragma unroll
  for (int j = 0; j < 2; ++j) gload16(vh + (size_t)krow[j] * S_ALL + kcol[j], &lV[0][kdst[j]]);
  __syncthreads();

  int cur = 0;
  for (int t = 0; t < 30; ++t) {
    const int kb = t * 64;
    if (t < 29) {  // stage tile t+1 into buf cur^1 (overlaps compute below)
#pragma unroll
      for (int j = 0; j < 2; ++j)
        gload16(kh + (size_t)(kb + 64 + krow[j]) * HD + kcol[j], &lK[cur ^ 1][kdst[j]]);
#pragma unroll
      for (int j = 0; j < 2; ++j)
        gload16(vh + (size_t)krow[j] * S_ALL + (kb + 64 + kcol[j]), &lV[cur ^ 1][kdst[j]]);
    }
    if (active) {
      const short* Kt = &lK[cur][0];
      const short* Vt = &lV[cur][0];
      f32x4 st[4];
      __builtin_amdgcn_s_setprio(1);
#pragma unroll
      for (int k16 = 0; k16 < 4; ++k16) {
        const int row = k16 * 16 + lr;
        const int m8 = (row & 7) * 8;
        short8 kf0 = *(const short8*)(Kt + row * 64 + ((lg * 8) ^ m8));
        short8 kf1 = *(const short8*)(Kt + row * 64 + ((32 + lg * 8) ^ m8));
        st[k16] = __builtin_amdgcn_mfma_f32_16x16x32_bf16(kf0, aq0, z4, 0, 0, 0);
        st[k16] = __builtin_amdgcn_mfma_f32_16x16x32_bf16(kf1, aq1, st[k16], 0, 0, 0);
      }
      __builtin_amdgcn_s_setprio(0);
      // max-free softmax: P = exp2(s) directly; per-lane partial l (no in-loop shfl)
      float rs = 0.f;
#pragma unroll
      for (int k16 = 0; k16 < 4; ++k16) {
        float p0 = __builtin_exp2f(st[k16][0]);
        float p1 = __builtin_exp2f(st[k16][1]);
        float p2 = __builtin_exp2f(st[k16][2]);
        float p3 = __builtin_exp2f(st[k16][3]);
        rs += (p0 + p1) + (p2 + p3);
        uint2 pk;
        asm("v_cvt_pk_bf16_f32 %0, %1, %2" : "=v"(pk.x) : "v"(p0), "v"(p1));
        asm("v_cvt_pk_bf16_f32 %0, %1, %2" : "=v"(pk.y) : "v"(p2), "v"(p3));
        *(uint2*)(lpw + lr * 64 + ((k16 * 16 + lg * 4) ^ pmask)) = pk;
      }
      lw += rs;
      asm volatile("s_waitcnt lgkmcnt(0)" ::: "memory");  // wave-synchronous LDS handoff
      short8 pa0 = *(const short8*)(lpw + lr * 64 + ((lg * 8) ^ pmask));
      short8 pa1 = *(const short8*)(lpw + lr * 64 + ((32 + lg * 8) ^ pmask));
      __builtin_amdgcn_s_setprio(1);
#pragma unroll
      for (int gd = 0; gd < 4; ++gd) {
        const int row = gd * 16 + lr;
        const int m8 = (row & 7) * 8;
        short8 vf0 = *(const short8*)(Vt + row * 64 + ((lg * 8) ^ m8));
        short8 vf1 = *(const short8*)(Vt + row * 64 + ((32 + lg * 8) ^ m8));
        f32x4 tacc = __builtin_amdgcn_mfma_f32_16x16x32_bf16(pa0, vf0, oa[gd], 0, 0, 0);
        oa[gd] = __builtin_amdgcn_mfma_f32_16x16x32_bf16(pa1, vf1, tacc, 0, 0, 0);
      }
      __builtin_amdgcn_s_setprio(0);
    }
    __syncthreads();
    cur ^= 1;
  }

  if (active) {  // tail: 32 keys [1920,1952), K/V direct from global (in-bounds exactly)
    const u16* kp = kh + (size_t)1920 * HD;
    short8 kf00 = *(const short8*)(kp + (size_t)lr * HD + lg * 8);
    short8 kf01 = *(const short8*)(kp + (size_t)lr * HD + 32 + lg * 8);
    short8 kf10 = *(const short8*)(kp + (size_t)(16 + lr) * HD + lg * 8);
    short8 kf11 = *(const short8*)(kp + (size_t)(16 + lr) * HD + 32 + lg * 8);
    f32x4 st0 = __builtin_amdgcn_mfma_f32_16x16x32_bf16(kf00, aq0, z4, 0, 0, 0);
    st0 = __builtin_amdgcn_mfma_f32_16x16x32_bf16(kf01, aq1, st0, 0, 0, 0);
    f32x4 st1 = __builtin_amdgcn_mfma_f32_16x16x32_bf16(kf10, aq0, z4, 0, 0, 0);
    st1 = __builtin_amdgcn_mfma_f32_16x16x32_bf16(kf11, aq1, st1, 0, 0, 0);
    float rs = 0.f;
    float pp[8];
#pragma unroll
    for (int r = 0; r < 4; ++r) { pp[r] = __builtin_exp2f(st0[r]); rs += pp[r]; }
#pragma unroll
    for (int r = 0; r < 4; ++r) { pp[4 + r] = __builtin_exp2f(st1[r]); rs += pp[4 + r]; }
    {
      uint2 pk;
      asm("v_cvt_pk_bf16_f32 %0, %1, %2" : "=v"(pk.x) : "v"(pp[0]), "v"(pp[1]));
      asm("v_cvt_pk_bf16_f32 %0, %1, %2" : "=v"(pk.y) : "v"(pp[2]), "v"(pp[3]));
      *(uint2*)(lpw + lr * 64 + ((lg * 4) ^ pmask)) = pk;
      asm("v_cvt_pk_bf16_f32 %0, %1, %2" : "=v"(pk.x) : "v"(pp[4]), "v"(pp[5]));
      asm("v_cvt_pk_bf16_f32 %0, %1, %2" : "=v"(pk.y) : "v"(pp[6]), "v"(pp[7]));
      *(uint2*)(lpw + lr * 64 + ((16 + lg * 4) ^ pmask)) = pk;
    }
    lw += rs;
    asm volatile("s_waitcnt lgkmcnt(0)" ::: "memory");
    short8 pa0 = *(const short8*)(lpw + lr * 64 + ((lg * 8) ^ pmask));
#pragma unroll
    for (int gd = 0; gd < 4; ++gd) {
      short8 vf = *(const short8*)(vh + (size_t)(gd * 16 + lr) * S_ALL + 1920 + lg * 8);
      oa[gd] = __builtin_amdgcn_mfma_f32_16x16x32_bf16(pa0, vf, oa[gd], 0, 0, 0);
    }
    // deferred l-reduction: sum the 4 lane-group partials once, then distribute
    lw += __shfl_xor(lw, 16);
    lw += __shfl_xor(lw, 32);
    // final: O[q][hh*64+d], q at reg dim (lg*4+r), d at lr dim
    float lwp[4];
#pragma unroll
    for (int r = 0; r < 4; ++r) lwp[r] = 1.0f / __shfl(lw, lg * 4 + r);
#pragma unroll
    for (int gd = 0; gd < 4; ++gd) {
      const int col = hh * HD + gd * 16 + lr;
#pragma unroll
      for (int r = 0; r < 4; ++r) {
        const int m = qbase + lg * 4 + r;
        o[(size_t)m * C_DIM + col] = f2b(oa[gd][r] * lwp[r]);
      }
    }
  }
}

// ---------------- launch ------------------------------------------------------------
extern "C" void kernel_launch(void* const* d_in, const int* in_sizes, int n_in,
                              void* d_out, int out_size, void* d_ws, size_t ws_size,
                              hipStream_t stream) {
  const float* hidden = (const float*)d_in[0];
  const float* enc = (const float*)d_in[1];
  const float* cosp = (const float*)d_in[2];
  const float* sinp = (const float*)d_in[3];
  const float* w1 = (const float*)d_in[4];
  const float* w2 = (const float*)d_in[5];
  const float* bq = (const float*)d_in[7];
  const float* bk = (const float*)d_in[9];
  const float* bv = (const float*)d_in[11];
  const float* bo = (const float*)d_in[13];
  u16* ws = (u16*)d_ws;
  float* out = (float*)d_out;

  prep_kernel<<<20796, 256, 0, stream>>>(hidden, enc, w1, w2, (const float*)d_in[6],
                                         (const float*)d_in[8], (const float*)d_in[10],
                                         (const float*)d_in[12], ws);

  GArgs c1{};  // conv1 split-K: M=1728 N=128, 6 slices x 30 steps, f32 partials
  c1.A = ws + OFF_XPAD; c1.B0 = c1.B1 = c1.B2 = ws + OFF_W1T;
  c1.lda = C_DIM; c1.ldb = 5760; c1.ksteps = 30; c1.spt = 60; c1.tap_rows = 216;
  c1.nMt = 27; c1.nNt = 2; c1.Mvalid = VID;
  c1.outf = (float*)(ws + OFF_Q);
  gemm_bt<64, 64, 4><<<324, 256, 0, stream>>>(c1);

  c1reduce_kernel<<<864, 256, 0, stream>>>((const float*)(ws + OFF_Q),
                                           ws + OFF_HG + (size_t)216 * RANK);

  GArgs c2{};  // conv2: M=1728 N=1920 K=3x128, 64x128 tiles -> 405 blocks
  c2.A = ws + OFF_HG; c2.B0 = c2.B1 = c2.B2 = ws + OFF_W2T;
  c2.lda = RANK; c2.ldb = 384; c2.ksteps = 12; c2.spt = 4; c2.tap_rows = 216;
  c2.nMt = 27; c2.nNt = 15; c2.Mvalid = VID; c2.hidden = hidden;
  c2.out0 = ws + OFF_HS + (size_t)TXT * C_DIM;
  gemm_bt<64, 128, 1><<<405, 256, 0, stream>>>(c2);

  GArgs c3{};  // fused QKV: M=1952 N=3x1920 K=1920, 128x128 KU=1 (proven best)
  c3.A = ws + OFF_HS; c3.B0 = ws + OFF_WQ; c3.B1 = ws + OFF_WK; c3.B2 = ws + OFF_WV;
  c3.bias0 = bq; c3.bias1 = bk; c3.bias2 = bv; c3.cosp = cosp; c3.sinp = sinp;
  c3.lda = C_DIM; c3.ldb = C_DIM; c3.ksteps = 60; c3.spt = 60; c3.tap_rows = 0;
  c3.nMt = 16; c3.nNt = 45; c3.Mvalid = S_ALL;
  c3.out0 = ws + OFF_Q; c3.out1 = ws + OFF_K; c3.out2 = ws + OFF_O;
  gemm_bt<128, 128, 2><<<720, 256, 0, stream>>>(c3);

  vtrans_kernel<<<930, 256, 0, stream>>>(ws + OFF_O, ws + OFF_V);  // V -> d-major

  attn_kernel<<<930, 256, 0, stream>>>(ws + OFF_Q, ws + OFF_K, ws + OFF_V, ws + OFF_O);

  GArgs c4{};  // out-proj: M=1952 N=1920 K=1920, 64x128 direct-store (r10 proven)
  c4.A = ws + OFF_O; c4.B0 = c4.B1 = c4.B2 = ws + OFF_WO; c4.bias0 = bo;
  c4.lda = C_DIM; c4.ldb = C_DIM; c4.ksteps = 60; c4.spt = 60; c4.tap_rows = 0;
  c4.nMt = 32; c4.nNt = 15; c4.Mvalid = S_ALL;
  c4.outf = out;
  gemm_bt<64, 128, 3><<<480, 256, 0, stream>>>(c4);
}